// Round 5
// baseline (91.659 us; speedup 1.0000x reference)
//
#include <hip/hip_runtime.h>
#include <math.h>

#define NN 4096

typedef float fvec4 __attribute__((ext_vector_type(4)));

// Expected output (harness casts complex64 ref .astype(float32) -> REAL part):
//   out[b,u,v] = -sgn(u-v) * p[b,u] * p[b,v] * sin(2(u-v))
//   p[b,x] = sqrt(0.5) * sqrt(|V[b,x]| + 1e-10) / (1 + x)
//
// One block per (b,u) row (16384 blocks). Per block:
//  - 64-entry hi/lo angle tables (f64 trig, f32 stored): cos/sin(2v) by
//    angle addition with v = 64*vhi + vlo.
//  - p-row staged in LDS (16 KB).
// Inner loop: 4 consecutive v per thread -> one float4 nontemporal store.
__global__ __launch_bounds__(256) void bs_main(const float* __restrict__ V,
                                               int nV,
                                               float* __restrict__ out,
                                               long long out_floats) {
    __shared__ float chi[64], shi[64], clo[64], slo[64];
    __shared__ float ptab[NN];

    const int t = threadIdx.x;
    const int row = blockIdx.x;          // 0 .. rows-1   (row = b*4096 + u)
    const int b = row >> 12;
    const int u = row & (NN - 1);

    if (t < 64) {
        double a = 128.0 * (double)t;    // 2 * (64 * t)
        chi[t] = (float)cos(a);
        shi[t] = (float)sin(a);
    } else if (t < 128) {
        const int k = t - 64;
        double a = 2.0 * (double)k;
        clo[k] = (float)cos(a);
        slo[k] = (float)sin(a);
    }

    const int vbase = b << 12;
    for (int i = t; i < NN; i += 256) {
        const int gi = vbase + i;
        const float v = (gi < nV) ? V[gi] : 0.0f;
        ptab[i] = 0.70710678118654752f * sqrtf(fabsf(v) + 1e-10f)
                  / (1.0f + (float)i);
    }
    __syncthreads();

    const int uh = u >> 6, ul = u & 63;
    const float cu = chi[uh] * clo[ul] - shi[uh] * slo[ul];   // cos(2u)
    const float su = shi[uh] * clo[ul] + chi[uh] * slo[ul];   // sin(2u)
    const float pu = ptab[u];

    const long long rowbase = (long long)row * NN;            // float index

    for (int j = t; j < NN / 4; j += 256) {
        const int v0 = 4 * j;            // 4-aligned: same hi index for all 4
        const int h = v0 >> 6;
        const int l = v0 & 63;

        const float ch = chi[h], sh = shi[h];

        fvec4 o;
        #pragma unroll
        for (int k = 0; k < 4; ++k) {
            const int v = v0 + k;
            const float cl = clo[l + k], sl = slo[l + k];
            const float cv = ch * cl - sh * sl;      // cos(2v)
            const float sv = sh * cl + ch * sl;      // sin(2v)
            const float sind = su * cv - cu * sv;    // sin(2(u-v))
            const float sg = (u > v) ? 1.0f : ((u < v) ? -1.0f : 0.0f);
            o[k] = -sg * pu * ptab[v] * sind;        // Re K(u,v)
        }

        const long long base = rowbase + (long long)v0;
        if (base + 4 <= out_floats) {                // guarded store
            __builtin_nontemporal_store(o, (fvec4*)(out + base));
        }
    }
}

extern "C" void kernel_launch(void* const* d_in, const int* in_sizes, int n_in,
                              void* d_out, int out_size, void* d_ws, size_t ws_size,
                              hipStream_t stream) {
    const float* V = (const float*)d_in[0];
    const int nV = in_sizes[0];                       // B*N = 16384 expected

    long long out_floats = (long long)out_size;       // one float per (b,u,v)
    long long rows_ll = out_floats / NN;
    int rows = (int)((rows_ll < (long long)nV) ? rows_ll : (long long)nV);
    if (rows <= 0) return;

    bs_main<<<rows, 256, 0, stream>>>(V, nV, (float*)d_out, out_floats);
}

// Round 6
// 58.659 us; speedup vs baseline: 1.5626x; 1.5626x over previous
//
#include <hip/hip_runtime.h>
#include <math.h>

#define NN 4096
#define ROWS 16

typedef float fvec4 __attribute__((ext_vector_type(4)));

// out[b,u,v] = -sgn(u-v) * p[b,u] * p[b,v] * sin(2(u-v))   (Re of the
// complex64 ref; harness casts .astype(float32))
//   p[b,x] = sqrt(0.5) * sqrt(|V[b,x]| + 1e-10) / (1 + x)
//
// One block per 16 consecutive u-rows (same b; 16 | 4096 so no straddle).
// Per block (amortized over 16 rows = 256 KB of output):
//  - 64-entry hi/lo angle tables from f64 trig (threads 0..127),
//  - full LDS tables ptab/ctab/stab[4096] (p, cos(2v), sin(2v)),
// Inner loop: float4 LDS reads (ds_read_b128, conflict-free) -> 4 outputs
// -> one float4 nontemporal store. Stores guarded by out_floats.
__global__ __launch_bounds__(256) void bs_main(const float* __restrict__ V,
                                               int nV,
                                               float* __restrict__ out,
                                               long long out_floats) {
    __shared__ float chi[64], shi[64], clo[64], slo[64];
    __shared__ float ptab[NN];
    __shared__ float ctab[NN];
    __shared__ float stab[NN];

    const int t = threadIdx.x;
    const int row0 = blockIdx.x * ROWS;
    const int b = row0 >> 12;                 // N == 4096

    if (t < 64) {
        double a = 128.0 * (double)t;         // 2 * (64*t)
        chi[t] = (float)cos(a);
        shi[t] = (float)sin(a);
    } else if (t < 128) {
        const int k = t - 64;
        double a = 2.0 * (double)k;
        clo[k] = (float)cos(a);
        slo[k] = (float)sin(a);
    }
    __syncthreads();                          // hi/lo tables ready

    const int vbase = b << 12;
    for (int i = t; i < NN; i += 256) {
        const int gi = vbase + i;
        const float v = (gi < nV) ? V[gi] : 0.0f;
        ptab[i] = 0.70710678118654752f * sqrtf(fabsf(v) + 1e-10f)
                  / (1.0f + (float)i);
        const int h = i >> 6, l = i & 63;
        ctab[i] = chi[h] * clo[l] - shi[h] * slo[l];   // cos(2i)
        stab[i] = shi[h] * clo[l] + chi[h] * slo[l];   // sin(2i)
    }
    __syncthreads();

    for (int r = 0; r < ROWS; ++r) {
        const int row = row0 + r;
        const int u = row & (NN - 1);
        const float cu = ctab[u];             // broadcast reads
        const float su = stab[u];
        const float pu = ptab[u];
        const long long rowbase = (long long)row * NN;

        for (int j = t; j < NN / 4; j += 256) {
            const int v0 = 4 * j;
            const fvec4 p4 = *(const fvec4*)&ptab[v0];   // ds_read_b128
            const fvec4 c4 = *(const fvec4*)&ctab[v0];
            const fvec4 s4 = *(const fvec4*)&stab[v0];

            fvec4 o;
            #pragma unroll
            for (int k = 0; k < 4; ++k) {
                const int v = v0 + k;
                const float sind = su * c4[k] - cu * s4[k];  // sin(2(u-v))
                const float m = pu * p4[k] * sind;
                o[k] = (u > v) ? -m : ((u < v) ? m : 0.0f);  // -sgn(u-v)*m
            }

            const long long base = rowbase + v0;
            if (base + 4 <= out_floats) {
                __builtin_nontemporal_store(o, (fvec4*)(out + base));
            }
        }
    }
}

extern "C" void kernel_launch(void* const* d_in, const int* in_sizes, int n_in,
                              void* d_out, int out_size, void* d_ws, size_t ws_size,
                              hipStream_t stream) {
    const float* V = (const float*)d_in[0];
    const int nV = in_sizes[0];                       // B*N = 16384 expected

    long long out_floats = (long long)out_size;       // one float per (b,u,v)
    long long rows_ll = out_floats / NN;
    if (rows_ll <= 0) return;
    int grid = (int)((rows_ll + ROWS - 1) / ROWS);

    bs_main<<<grid, 256, 0, stream>>>(V, nV, (float*)d_out, out_floats);
}